// Round 1
// baseline (193.800 us; speedup 1.0000x reference)
//
#include <hip/hip_runtime.h>
#include <math.h>

#define B_  16
#define N_  8192
#define D_  128
#define H_  64
#define E_  64
#define EPSLN 1e-5f

// workspace layout in floats
#define WS_MU    0
#define WS_RS    (WS_MU + B_*N_)
#define WS_COL   (WS_RS + B_*N_)
#define WS_M     (WS_COL + B_*D_)
#define WS_T     (WS_M + B_*D_*E_)
#define WS_C     (WS_T + B_*E_)

// ---------------------------------------------------------------------------
// Kernel A: per-row layernorm stats (mu, rsig) + per-batch column accumulation
//   colacc[b,d] = sum_i rsig_i * (x[b,i,d] - mu_i)
// One wave processes one row at a time (64 lanes x float2 = 128 values).
// ---------------------------------------------------------------------------
__global__ __launch_bounds__(256) void k_stats(const float* __restrict__ x,
                                               float* __restrict__ mu_g,
                                               float* __restrict__ rs_g,
                                               float* __restrict__ colacc) {
    int b = blockIdx.y;
    int t = threadIdx.x;
    int wave = t >> 6, lane = t & 63;
    int rowbase = blockIdx.x * 256 + wave * 64;

    const float2* xp = (const float2*)x;
    size_t base = (size_t)(b * N_ + rowbase) * (D_ / 2) + lane;

    float cx = 0.f, cy = 0.f;
    for (int i = 0; i < 64; ++i) {
        float2 v = xp[base + (size_t)i * (D_ / 2)];
        float s  = v.x + v.y;
        float s2 = v.x * v.x + v.y * v.y;
#pragma unroll
        for (int off = 32; off >= 1; off >>= 1) {
            s  += __shfl_xor(s,  off, 64);
            s2 += __shfl_xor(s2, off, 64);
        }
        float mu  = s * (1.f / D_);
        float var = s2 * (1.f / D_) - mu * mu;
        float rs  = rsqrtf(var + EPSLN);
        if (lane == 0) {
            mu_g[b * N_ + rowbase + i] = mu;
            rs_g[b * N_ + rowbase + i] = rs;
        }
        cx += rs * (v.x - mu);
        cy += rs * (v.y - mu);
    }

    __shared__ float2 red[256];
    red[t] = make_float2(cx, cy);
    __syncthreads();
    if (t < 64) {
        float2 a  = red[t];
        float2 b1 = red[t + 64], b2 = red[t + 128], b3 = red[t + 192];
        a.x += b1.x + b2.x + b3.x;
        a.y += b1.y + b2.y + b3.y;
        atomicAdd(&colacc[b * D_ + 2 * t],     a.x);
        atomicAdd(&colacc[b * D_ + 2 * t + 1], a.y);
    }
}

// ---------------------------------------------------------------------------
// Kernel B: tiny per-batch combine.
//   cm[d]  = ln_w[d]*colacc[b,d]/N + ln_b[d]          (colmean of xn)
//   ml[h]  = cm . Wl[:,h] + bl[h]                     (mean of left)
//   P[h,e] = ml[h]*Wo[h,e]
//   M[d,e] = ln_w[d] * sum_h Wr[d,h]*P[h,e]
//   T[e]   = sum_h (sum_d ln_w[d]*Wr[d,h]) * P[h,e]   (= colsum of M)
//   C[e]   = sum_h (sum_d ln_b[d]*Wr[d,h] + br[h]) * P[h,e] + bo[e]
// grid (4, B): each block computes a 32-d slice of M; block dblk==0 does T,C.
// ---------------------------------------------------------------------------
__global__ __launch_bounds__(256) void k_combine(const float* __restrict__ colacc,
                                                 const float* __restrict__ ln_w,
                                                 const float* __restrict__ ln_b,
                                                 const float* __restrict__ Wl,
                                                 const float* __restrict__ bl,
                                                 const float* __restrict__ Wr,
                                                 const float* __restrict__ br,
                                                 const float* __restrict__ Wo,
                                                 const float* __restrict__ bo,
                                                 float* __restrict__ Mg,
                                                 float* __restrict__ Tg,
                                                 float* __restrict__ Cg) {
    int b = blockIdx.y, dblk = blockIdx.x, t = threadIdx.x;
    __shared__ float cm[D_], ml[H_], uu[H_], qq[H_];
    __shared__ float P[H_ * E_];

    if (t < D_) cm[t] = ln_w[t] * colacc[b * D_ + t] * (1.f / N_) + ln_b[t];
    __syncthreads();

    if (t < H_) {
        float a = bl[t], u = 0.f, q = 0.f;
        for (int d = 0; d < D_; ++d) {
            float wr = Wr[d * H_ + t];
            a += cm[d] * Wl[d * H_ + t];
            u += ln_w[d] * wr;
            q += ln_b[d] * wr;
        }
        ml[t] = a; uu[t] = u; qq[t] = q + br[t];
    }
    __syncthreads();

#pragma unroll
    for (int k = 0; k < 16; ++k) {
        int idx = t + 256 * k;
        P[idx] = ml[idx >> 6] * Wo[idx];
    }
    __syncthreads();

    int d  = dblk * 32 + (t >> 3);
    int eo = (t & 7) * 8;
    float a0 = 0, a1 = 0, a2 = 0, a3 = 0, a4 = 0, a5 = 0, a6 = 0, a7 = 0;
    for (int h = 0; h < H_; ++h) {
        float wr = Wr[d * H_ + h];
        const float4* p4 = (const float4*)&P[h * E_ + eo];
        float4 pa = p4[0], pb = p4[1];
        a0 += wr * pa.x; a1 += wr * pa.y; a2 += wr * pa.z; a3 += wr * pa.w;
        a4 += wr * pb.x; a5 += wr * pb.y; a6 += wr * pb.z; a7 += wr * pb.w;
    }
    float wd = ln_w[d];
    float4* Mo = (float4*)&Mg[(size_t)b * D_ * E_ + d * E_ + eo];
    Mo[0] = make_float4(wd * a0, wd * a1, wd * a2, wd * a3);
    Mo[1] = make_float4(wd * a4, wd * a5, wd * a6, wd * a7);

    if (dblk == 0 && t < E_) {
        float T = 0.f, C = bo[t];
        for (int h = 0; h < H_; ++h) {
            float p = P[h * E_ + t];
            T += uu[h] * p;
            C += qq[h] * p;
        }
        Tg[b * E_ + t] = T;
        Cg[b * E_ + t] = C;
    }
}

// ---------------------------------------------------------------------------
// Kernel C: out[b,j,e] = rsig_j*( x[b,j,:].M[b][:,e] - mu_j*T[b,e] ) + C[b,e]
// 256 rows per block, 8x8 register tile per thread, M + transposed x in LDS.
// ---------------------------------------------------------------------------
__global__ __launch_bounds__(256, 2) void k_gemm(const float* __restrict__ x,
                                                 const float* __restrict__ mu_g,
                                                 const float* __restrict__ rs_g,
                                                 const float* __restrict__ Mg,
                                                 const float* __restrict__ Tg,
                                                 const float* __restrict__ Cg,
                                                 float* __restrict__ out) {
    __shared__ float Ml[D_ * E_];   // 32 KB
    __shared__ float xt[32 * 256];  // 32 KB, xt[d_local*256 + row_in_block]
    __shared__ float Tl[E_], Cl[E_], mul[256], rsl[256];

    int b = blockIdx.y, t = threadIdx.x;
    int rowbase = blockIdx.x * 256;

    // stage M (8192 floats), T, C, mu/rsig for this block's 256 rows
    const float4* Ms = (const float4*)(Mg + (size_t)b * D_ * E_);
    float4* Md = (float4*)Ml;
#pragma unroll
    for (int k = 0; k < 8; ++k) Md[t + 256 * k] = Ms[t + 256 * k];
    if (t < E_) { Tl[t] = Tg[b * E_ + t]; Cl[t] = Cg[b * E_ + t]; }
    int rg = b * N_ + rowbase + t;
    mul[t] = mu_g[rg];
    rsl[t] = rs_g[rg];

    int wave = t >> 6, lane = t & 63;
    int tr = lane >> 3, te = lane & 7;
    int xbase = wave * 64 + tr * 8;  // this thread's first row (within block)
    int ebase = te * 8;              // this thread's first output column

    const float4* xrow = (const float4*)(x + (size_t)rg * D_);

    float acc[8][8];
#pragma unroll
    for (int i = 0; i < 8; ++i)
#pragma unroll
        for (int j = 0; j < 8; ++j) acc[i][j] = 0.f;

    for (int c = 0; c < 4; ++c) {
        // stage 32 d-columns of x, transposed (thread t owns row t of block)
#pragma unroll
        for (int j = 0; j < 8; ++j) {
            float4 v = xrow[c * 8 + j];
            xt[(j * 4 + 0) * 256 + t] = v.x;
            xt[(j * 4 + 1) * 256 + t] = v.y;
            xt[(j * 4 + 2) * 256 + t] = v.z;
            xt[(j * 4 + 3) * 256 + t] = v.w;
        }
        __syncthreads();

#pragma unroll 4
        for (int dl = 0; dl < 32; ++dl) {
            const float* xp = &xt[dl * 256 + xbase];
            float4 xa = *(const float4*)xp;
            float4 xb = *(const float4*)(xp + 4);
            const float* mp = &Ml[(c * 32 + dl) * E_ + ebase];
            float4 ma = *(const float4*)mp;
            float4 mb = *(const float4*)(mp + 4);
            float xs[8] = {xa.x, xa.y, xa.z, xa.w, xb.x, xb.y, xb.z, xb.w};
            float ms[8] = {ma.x, ma.y, ma.z, ma.w, mb.x, mb.y, mb.z, mb.w};
#pragma unroll
            for (int i = 0; i < 8; ++i)
#pragma unroll
                for (int j = 0; j < 8; ++j) acc[i][j] += xs[i] * ms[j];
        }
        __syncthreads();
    }

    // epilogue: out = rsig*(acc - mu*T) + C
    size_t outbase = (size_t)(b * N_ + rowbase) * E_;
#pragma unroll
    for (int i = 0; i < 8; ++i) {
        int r = xbase + i;
        float m = mul[r], rs = rsl[r];
        float4 o0, o1;
        o0.x = rs * (acc[i][0] - m * Tl[ebase + 0]) + Cl[ebase + 0];
        o0.y = rs * (acc[i][1] - m * Tl[ebase + 1]) + Cl[ebase + 1];
        o0.z = rs * (acc[i][2] - m * Tl[ebase + 2]) + Cl[ebase + 2];
        o0.w = rs * (acc[i][3] - m * Tl[ebase + 3]) + Cl[ebase + 3];
        o1.x = rs * (acc[i][4] - m * Tl[ebase + 4]) + Cl[ebase + 4];
        o1.y = rs * (acc[i][5] - m * Tl[ebase + 5]) + Cl[ebase + 5];
        o1.z = rs * (acc[i][6] - m * Tl[ebase + 6]) + Cl[ebase + 6];
        o1.w = rs * (acc[i][7] - m * Tl[ebase + 7]) + Cl[ebase + 7];
        float4* op = (float4*)&out[outbase + (size_t)r * E_ + ebase];
        op[0] = o0;
        op[1] = o1;
    }
}

extern "C" void kernel_launch(void* const* d_in, const int* in_sizes, int n_in,
                              void* d_out, int out_size, void* d_ws, size_t ws_size,
                              hipStream_t stream) {
    const float* x    = (const float*)d_in[0];
    const float* ln_w = (const float*)d_in[1];
    const float* ln_b = (const float*)d_in[2];
    const float* Wl   = (const float*)d_in[3];
    const float* bl   = (const float*)d_in[4];
    const float* Wr   = (const float*)d_in[5];
    const float* br   = (const float*)d_in[6];
    const float* Wo   = (const float*)d_in[7];
    const float* bo   = (const float*)d_in[8];
    float* out = (float*)d_out;
    float* ws  = (float*)d_ws;

    float* mu_g   = ws + WS_MU;
    float* rs_g   = ws + WS_RS;
    float* colacc = ws + WS_COL;
    float* Mg     = ws + WS_M;
    float* Tg     = ws + WS_T;
    float* Cg     = ws + WS_C;

    // zero the atomic accumulator (ws is poisoned 0xAA before every launch)
    hipMemsetAsync(colacc, 0, B_ * D_ * sizeof(float), stream);

    k_stats<<<dim3(N_ / 256, B_), 256, 0, stream>>>(x, mu_g, rs_g, colacc);
    k_combine<<<dim3(4, B_), 256, 0, stream>>>(colacc, ln_w, ln_b, Wl, bl, Wr,
                                               br, Wo, bo, Mg, Tg, Cg);
    k_gemm<<<dim3(N_ / 256, B_), 256, 0, stream>>>(x, mu_g, rs_g, Mg, Tg, Cg, out);
}

// Round 2
// 169.497 us; speedup vs baseline: 1.1434x; 1.1434x over previous
//
#include <hip/hip_runtime.h>
#include <math.h>

#define B_  16
#define N_  8192
#define D_  128
#define H_  64
#define E_  64
#define EPSLN 1e-5f

// workspace layout in floats
#define WS_COL   0
#define WS_M     (WS_COL + B_*D_)
#define WS_T     (WS_M + B_*D_*E_)
#define WS_C     (WS_T + B_*E_)

// ---------------------------------------------------------------------------
// Kernel A: per-batch weighted column accumulation
//   colacc[b,d] = sum_i rsig_i * (x[b,i,d] - mu_i)
// Phase 1: one THREAD per row (no cross-lane ops) -> stats in LDS.
// Phase 2: coalesced column-major second read (L2-warm) + 1 atomic/col/half.
// ---------------------------------------------------------------------------
__global__ __launch_bounds__(256) void k_stats(const float* __restrict__ x,
                                               float* __restrict__ colacc) {
    __shared__ float mul[256], rsl[256];
    int b = blockIdx.y, t = threadIdx.x;
    int rowbase = blockIdx.x * 256;
    size_t g = (size_t)(b * N_ + rowbase);

    // phase 1: per-thread row stats (strided loads, deep ILP, no shuffles)
    const float4* xr = (const float4*)(x + (g + t) * D_);
    float s = 0.f, s2 = 0.f;
#pragma unroll 8
    for (int k = 0; k < 32; ++k) {
        float4 v = xr[k];
        s  += (v.x + v.y) + (v.z + v.w);
        s2 += (v.x * v.x + v.y * v.y) + (v.z * v.z + v.w * v.w);
    }
    float mu  = s * (1.f / D_);
    float var = s2 * (1.f / D_) - mu * mu;
    mul[t] = mu;
    rsl[t] = rsqrtf(var + EPSLN);
    __syncthreads();

    // phase 2: weighted colsum, coalesced (consecutive t -> consecutive col)
    int c = t & 127, half = t >> 7;
    const float* xp = x + (g + half * 128) * D_ + c;
    float acc = 0.f;
#pragma unroll 8
    for (int i = 0; i < 128; ++i) {
        acc += rsl[half * 128 + i] * (xp[(size_t)i * D_] - mul[half * 128 + i]);
    }
    atomicAdd(&colacc[b * D_ + c], acc);
}

// ---------------------------------------------------------------------------
// Kernel B: tiny per-batch combine.
//   cm[d]  = ln_w[d]*colacc[b,d]/N + ln_b[d]          (colmean of xn)
//   ml[h]  = cm . Wl[:,h] + bl[h]                     (mean of left)
//   P[h,e] = ml[h]*Wo[h,e]
//   M[d,e] = ln_w[d] * sum_h Wr[d,h]*P[h,e]
//   T[e]   = sum_h (sum_d ln_w[d]*Wr[d,h]) * P[h,e]   (= colsum of M)
//   C[e]   = sum_h (sum_d ln_b[d]*Wr[d,h] + br[h]) * P[h,e] + bo[e]
// grid (4, B): each block computes a 32-d slice of M; block dblk==0 does T,C.
// ---------------------------------------------------------------------------
__global__ __launch_bounds__(256) void k_combine(const float* __restrict__ colacc,
                                                 const float* __restrict__ ln_w,
                                                 const float* __restrict__ ln_b,
                                                 const float* __restrict__ Wl,
                                                 const float* __restrict__ bl,
                                                 const float* __restrict__ Wr,
                                                 const float* __restrict__ br,
                                                 const float* __restrict__ Wo,
                                                 const float* __restrict__ bo,
                                                 float* __restrict__ Mg,
                                                 float* __restrict__ Tg,
                                                 float* __restrict__ Cg) {
    int b = blockIdx.y, dblk = blockIdx.x, t = threadIdx.x;
    __shared__ float cm[D_], ml[H_], uu[H_], qq[H_];
    __shared__ float P[H_ * E_];

    if (t < D_) cm[t] = ln_w[t] * colacc[b * D_ + t] * (1.f / N_) + ln_b[t];
    __syncthreads();

    if (t < H_) {
        float a = bl[t], u = 0.f, q = 0.f;
        for (int d = 0; d < D_; ++d) {
            float wr = Wr[d * H_ + t];
            a += cm[d] * Wl[d * H_ + t];
            u += ln_w[d] * wr;
            q += ln_b[d] * wr;
        }
        ml[t] = a; uu[t] = u; qq[t] = q + br[t];
    }
    __syncthreads();

#pragma unroll
    for (int k = 0; k < 16; ++k) {
        int idx = t + 256 * k;
        P[idx] = ml[idx >> 6] * Wo[idx];
    }
    __syncthreads();

    int d  = dblk * 32 + (t >> 3);
    int eo = (t & 7) * 8;
    float a0 = 0, a1 = 0, a2 = 0, a3 = 0, a4 = 0, a5 = 0, a6 = 0, a7 = 0;
    for (int h = 0; h < H_; ++h) {
        float wr = Wr[d * H_ + h];
        const float4* p4 = (const float4*)&P[h * E_ + eo];
        float4 pa = p4[0], pb = p4[1];
        a0 += wr * pa.x; a1 += wr * pa.y; a2 += wr * pa.z; a3 += wr * pa.w;
        a4 += wr * pb.x; a5 += wr * pb.y; a6 += wr * pb.z; a7 += wr * pb.w;
    }
    float wd = ln_w[d];
    float4* Mo = (float4*)&Mg[(size_t)b * D_ * E_ + d * E_ + eo];
    Mo[0] = make_float4(wd * a0, wd * a1, wd * a2, wd * a3);
    Mo[1] = make_float4(wd * a4, wd * a5, wd * a6, wd * a7);

    if (dblk == 0 && t < E_) {
        float T = 0.f, C = bo[t];
        for (int h = 0; h < H_; ++h) {
            float p = P[h * E_ + t];
            T += uu[h] * p;
            C += qq[h] * p;
        }
        Tg[b * E_ + t] = T;
        Cg[b * E_ + t] = C;
    }
}

// ---------------------------------------------------------------------------
// Kernel C: out[b,j,e] = rsig_j*( x[b,j,:].M[b][:,e] - mu_j*T[b,e] ) + C[b,e]
// 256 rows per block, 8x8 register tile per thread, M + transposed x in LDS.
// LN stats (mu, rsig) recomputed inline from the rows we already load.
// ---------------------------------------------------------------------------
__global__ __launch_bounds__(256, 2) void k_gemm(const float* __restrict__ x,
                                                 const float* __restrict__ Mg,
                                                 const float* __restrict__ Tg,
                                                 const float* __restrict__ Cg,
                                                 float* __restrict__ out) {
    __shared__ float Ml[D_ * E_];   // 32 KB
    __shared__ float xt[32 * 256];  // 32 KB, xt[d_local*256 + row_in_block]
    __shared__ float Tl[E_], Cl[E_], mul[256], rsl[256];

    int b = blockIdx.y, t = threadIdx.x;
    int rowbase = blockIdx.x * 256;

    // stage M (8192 floats), T, C
    const float4* Ms = (const float4*)(Mg + (size_t)b * D_ * E_);
    float4* Md = (float4*)Ml;
#pragma unroll
    for (int k = 0; k < 8; ++k) Md[t + 256 * k] = Ms[t + 256 * k];
    if (t < E_) { Tl[t] = Tg[b * E_ + t]; Cl[t] = Cg[b * E_ + t]; }

    int wave = t >> 6, lane = t & 63;
    int tr = lane >> 3, te = lane & 7;
    int xbase = wave * 64 + tr * 8;  // this thread's first row (within block)
    int ebase = te * 8;              // this thread's first output column

    size_t grow = (size_t)(b * N_ + rowbase + t);
    const float4* xrow = (const float4*)(x + grow * D_);

    float acc[8][8];
#pragma unroll
    for (int i = 0; i < 8; ++i)
#pragma unroll
        for (int j = 0; j < 8; ++j) acc[i][j] = 0.f;

    float s = 0.f, s2 = 0.f;  // LN stats for the row this thread stages

    for (int c = 0; c < 4; ++c) {
        // stage 32 d-columns of x, transposed (thread t owns row t of block)
#pragma unroll
        for (int j = 0; j < 8; ++j) {
            float4 v = xrow[c * 8 + j];
            s  += (v.x + v.y) + (v.z + v.w);
            s2 += (v.x * v.x + v.y * v.y) + (v.z * v.z + v.w * v.w);
            xt[(j * 4 + 0) * 256 + t] = v.x;
            xt[(j * 4 + 1) * 256 + t] = v.y;
            xt[(j * 4 + 2) * 256 + t] = v.z;
            xt[(j * 4 + 3) * 256 + t] = v.w;
        }
        __syncthreads();

#pragma unroll 4
        for (int dl = 0; dl < 32; ++dl) {
            const float* xp = &xt[dl * 256 + xbase];
            float4 xa = *(const float4*)xp;
            float4 xb = *(const float4*)(xp + 4);
            const float* mp = &Ml[(c * 32 + dl) * E_ + ebase];
            float4 ma = *(const float4*)mp;
            float4 mb = *(const float4*)(mp + 4);
            float xs[8] = {xa.x, xa.y, xa.z, xa.w, xb.x, xb.y, xb.z, xb.w};
            float ms[8] = {ma.x, ma.y, ma.z, ma.w, mb.x, mb.y, mb.z, mb.w};
#pragma unroll
            for (int i = 0; i < 8; ++i)
#pragma unroll
                for (int j = 0; j < 8; ++j) acc[i][j] += xs[i] * ms[j];
        }
        __syncthreads();
    }

    // publish this row's LN stats
    {
        float mu  = s * (1.f / D_);
        float var = s2 * (1.f / D_) - mu * mu;
        mul[t] = mu;
        rsl[t] = rsqrtf(var + EPSLN);
    }
    __syncthreads();

    // epilogue: out = rsig*(acc - mu*T) + C
    size_t outbase = (size_t)(b * N_ + rowbase) * E_;
#pragma unroll
    for (int i = 0; i < 8; ++i) {
        int r = xbase + i;
        float m = mul[r], rs = rsl[r];
        float4 o0, o1;
        o0.x = rs * (acc[i][0] - m * Tl[ebase + 0]) + Cl[ebase + 0];
        o0.y = rs * (acc[i][1] - m * Tl[ebase + 1]) + Cl[ebase + 1];
        o0.z = rs * (acc[i][2] - m * Tl[ebase + 2]) + Cl[ebase + 2];
        o0.w = rs * (acc[i][3] - m * Tl[ebase + 3]) + Cl[ebase + 3];
        o1.x = rs * (acc[i][4] - m * Tl[ebase + 4]) + Cl[ebase + 4];
        o1.y = rs * (acc[i][5] - m * Tl[ebase + 5]) + Cl[ebase + 5];
        o1.z = rs * (acc[i][6] - m * Tl[ebase + 6]) + Cl[ebase + 6];
        o1.w = rs * (acc[i][7] - m * Tl[ebase + 7]) + Cl[ebase + 7];
        float4* op = (float4*)&out[outbase + (size_t)r * E_ + ebase];
        op[0] = o0;
        op[1] = o1;
    }
}

extern "C" void kernel_launch(void* const* d_in, const int* in_sizes, int n_in,
                              void* d_out, int out_size, void* d_ws, size_t ws_size,
                              hipStream_t stream) {
    const float* x    = (const float*)d_in[0];
    const float* ln_w = (const float*)d_in[1];
    const float* ln_b = (const float*)d_in[2];
    const float* Wl   = (const float*)d_in[3];
    const float* bl   = (const float*)d_in[4];
    const float* Wr   = (const float*)d_in[5];
    const float* br   = (const float*)d_in[6];
    const float* Wo   = (const float*)d_in[7];
    const float* bo   = (const float*)d_in[8];
    float* out = (float*)d_out;
    float* ws  = (float*)d_ws;

    float* colacc = ws + WS_COL;
    float* Mg     = ws + WS_M;
    float* Tg     = ws + WS_T;
    float* Cg     = ws + WS_C;

    // zero the atomic accumulator (ws is poisoned 0xAA before every launch)
    hipMemsetAsync(colacc, 0, B_ * D_ * sizeof(float), stream);

    k_stats<<<dim3(N_ / 256, B_), 256, 0, stream>>>(x, colacc);
    k_combine<<<dim3(4, B_), 256, 0, stream>>>(colacc, ln_w, ln_b, Wl, bl, Wr,
                                               br, Wo, bo, Mg, Tg, Cg);
    k_gemm<<<dim3(N_ / 256, B_), 256, 0, stream>>>(x, Mg, Tg, Cg, out);
}

// Round 3
// 145.148 us; speedup vs baseline: 1.3352x; 1.1678x over previous
//
#include <hip/hip_runtime.h>
#include <math.h>

#define B_  16
#define N_  8192
#define D_  128
#define H_  64
#define E_  64
#define EPSLN 1e-5f

typedef __attribute__((ext_vector_type(8))) short short8;
typedef __attribute__((ext_vector_type(4))) float f32x4;

// workspace layout (bytes):
//   colacc : B*D floats          @ 0        (8192 B)
//   Mt     : B*E*D bf16 (ushort) @ 8192     (262144 B)   Mt[b][e][d]
//   Tg     : B*E floats          @ 270336
//   Cg     : B*E floats          @ 274432
#define WSB_COL 0
#define WSB_MT  8192
#define WSB_T   270336
#define WSB_C   274432

static __device__ __forceinline__ unsigned short f2bf(float f) {
    union { float f; unsigned u; } c; c.f = f;
    unsigned u = c.u;
    return (unsigned short)((u + 0x7FFFu + ((u >> 16) & 1u)) >> 16);  // RNE
}

// ---------------------------------------------------------------------------
// Kernel A: colacc[b,d] = sum_i rsig_i * (x[b,i,d] - mu_i)
// Single global read: 64-row tile staged in LDS (pad +4 floats/row),
// stats via 4-lane groups, weighted colsum read column-wise from LDS.
// ---------------------------------------------------------------------------
__global__ __launch_bounds__(256) void k_stats(const float* __restrict__ x,
                                               float* __restrict__ colacc) {
    __shared__ float xs[64 * 132];           // 33.8 KB, row stride 132
    __shared__ float mul[64], rsl[64], red[128];
    int b = blockIdx.y, t = threadIdx.x;
    int rowbase = blockIdx.x * 64;
    size_t gbase = (size_t)(b * N_ + rowbase) * 32;  // in float4 units

    // stage: 2048 float4s, coalesced
    const float4* x4 = (const float4*)x;
#pragma unroll
    for (int k = 0; k < 8; ++k) {
        int idx = t + 256 * k;
        int row = idx >> 5, c4 = idx & 31;
        *(float4*)&xs[row * 132 + c4 * 4] = x4[gbase + idx];
    }
    __syncthreads();

    // stats: 4 threads per row
    {
        int r = t >> 2, q = t & 3;
        float s = 0.f, s2 = 0.f;
#pragma unroll
        for (int i = 0; i < 8; ++i) {
            float4 v = *(const float4*)&xs[r * 132 + q * 32 + i * 4];
            s  += (v.x + v.y) + (v.z + v.w);
            s2 += (v.x * v.x + v.y * v.y) + (v.z * v.z + v.w * v.w);
        }
        s  += __shfl_xor(s, 1, 64);  s  += __shfl_xor(s, 2, 64);
        s2 += __shfl_xor(s2, 1, 64); s2 += __shfl_xor(s2, 2, 64);
        if (q == 0) {
            float mu  = s * (1.f / D_);
            float var = s2 * (1.f / D_) - mu * mu;
            mul[r] = mu;
            rsl[r] = rsqrtf(var + EPSLN);
        }
    }
    __syncthreads();

    // weighted colsum: col c, half hh (rows hh*32..+31); 2-way banks = free
    int c = t & 127, hh = t >> 7;
    float acc = 0.f;
#pragma unroll 8
    for (int i = 0; i < 32; ++i) {
        int r = hh * 32 + i;
        acc += rsl[r] * (xs[r * 132 + c] - mul[r]);
    }
    if (hh == 1) red[c] = acc;
    __syncthreads();
    if (hh == 0) atomicAdd(&colacc[b * D_ + c], acc + red[c]);
}

// ---------------------------------------------------------------------------
// Kernel B: tiny per-batch combine; emits Mt (bf16, [e][d]), T, C.
//   cm[d]  = ln_w[d]*colacc[b,d]/N + ln_b[d]
//   ml[h]  = cm . Wl[:,h] + bl[h]
//   P[h,e] = ml[h]*Wo[h,e]
//   M[d,e] = ln_w[d] * sum_h Wr[d,h]*P[h,e]   -> stored transposed as bf16
//   T[e]   = colsum_d M[d,e];  C[e] = (ln_b.Wr + br) . P[:,e] + bo[e]
// ---------------------------------------------------------------------------
__global__ __launch_bounds__(256) void k_combine(const float* __restrict__ colacc,
                                                 const float* __restrict__ ln_w,
                                                 const float* __restrict__ ln_b,
                                                 const float* __restrict__ Wl,
                                                 const float* __restrict__ bl,
                                                 const float* __restrict__ Wr,
                                                 const float* __restrict__ br,
                                                 const float* __restrict__ Wo,
                                                 const float* __restrict__ bo,
                                                 unsigned short* __restrict__ Mt,
                                                 float* __restrict__ Tg,
                                                 float* __restrict__ Cg) {
    int b = blockIdx.y, dblk = blockIdx.x, t = threadIdx.x;
    __shared__ float cm[D_], ml[H_], uu[H_], qq[H_];
    __shared__ float P[H_ * E_];

    if (t < D_) cm[t] = ln_w[t] * colacc[b * D_ + t] * (1.f / N_) + ln_b[t];
    __syncthreads();

    if (t < H_) {
        float a = bl[t], u = 0.f, q = 0.f;
        for (int d = 0; d < D_; ++d) {
            float wr = Wr[d * H_ + t];
            a += cm[d] * Wl[d * H_ + t];
            u += ln_w[d] * wr;
            q += ln_b[d] * wr;
        }
        ml[t] = a; uu[t] = u; qq[t] = q + br[t];
    }
    __syncthreads();

#pragma unroll
    for (int k = 0; k < 16; ++k) {
        int idx = t + 256 * k;
        P[idx] = ml[idx >> 6] * Wo[idx];
    }
    __syncthreads();

    int d  = dblk * 32 + (t >> 3);
    int eo = (t & 7) * 8;
    float a0 = 0, a1 = 0, a2 = 0, a3 = 0, a4 = 0, a5 = 0, a6 = 0, a7 = 0;
    for (int h = 0; h < H_; ++h) {
        float wr = Wr[d * H_ + h];
        const float4* p4 = (const float4*)&P[h * E_ + eo];
        float4 pa = p4[0], pb = p4[1];
        a0 += wr * pa.x; a1 += wr * pa.y; a2 += wr * pa.z; a3 += wr * pa.w;
        a4 += wr * pb.x; a5 += wr * pb.y; a6 += wr * pb.z; a7 += wr * pb.w;
    }
    float wd = ln_w[d];
    size_t mb = (size_t)b * E_ * D_;
    Mt[mb + (size_t)(eo + 0) * D_ + d] = f2bf(wd * a0);
    Mt[mb + (size_t)(eo + 1) * D_ + d] = f2bf(wd * a1);
    Mt[mb + (size_t)(eo + 2) * D_ + d] = f2bf(wd * a2);
    Mt[mb + (size_t)(eo + 3) * D_ + d] = f2bf(wd * a3);
    Mt[mb + (size_t)(eo + 4) * D_ + d] = f2bf(wd * a4);
    Mt[mb + (size_t)(eo + 5) * D_ + d] = f2bf(wd * a5);
    Mt[mb + (size_t)(eo + 6) * D_ + d] = f2bf(wd * a6);
    Mt[mb + (size_t)(eo + 7) * D_ + d] = f2bf(wd * a7);

    if (dblk == 0 && t < E_) {
        float T = 0.f, C = bo[t];
        for (int h = 0; h < H_; ++h) {
            float p = P[h * E_ + t];
            T += uu[h] * p;
            C += qq[h] * p;
        }
        Tg[b * E_ + t] = T;
        Cg[b * E_ + t] = C;
    }
}

// ---------------------------------------------------------------------------
// Kernel C (MFMA bf16): out[b,j,e] = rsig_j*(x_j . M[:,e]) - rsig_j*mu_j*T[e] + C[e]
// 256-row tile. x staged to LDS as bf16 with XOR-swizzled 16B granules
// (granule g of row r stored at g ^ (r&15)): conflict-free b128 frag reads,
// rows 16B-aligned, no padding. M read as bf16 from global (L1-resident).
// One barrier; K fully unrolled (4 chunks of 32); per wave 4x4 16x16 tiles.
// LN stats computed inline during staging.
// ---------------------------------------------------------------------------
__global__ __launch_bounds__(256, 2) void k_gemm(const float* __restrict__ x,
                                                 const unsigned short* __restrict__ Mt,
                                                 const float* __restrict__ Tg,
                                                 const float* __restrict__ Cg,
                                                 float* __restrict__ out) {
    __shared__ short xs[256 * 128];  // 64 KB bf16
    __shared__ float mul[256], rsl[256], Tl[E_], Cl[E_];

    int b = blockIdx.y, t = threadIdx.x;
    int rowbase = blockIdx.x * 256;

    if (t < E_) { Tl[t] = Tg[b * E_ + t]; Cl[t] = Cg[b * E_ + t]; }

    // ---- stage row t: global fp32 -> bf16 LDS (swizzled), stats inline ----
    {
        const float4* xrow = (const float4*)(x + (size_t)(b * N_ + rowbase + t) * D_);
        float s = 0.f, s2 = 0.f;
        int sw = t & 15;
#pragma unroll
        for (int g = 0; g < 16; ++g) {          // 16B granule = 8 bf16
            float4 va = xrow[2 * g], vb = xrow[2 * g + 1];
            s  += (va.x + va.y) + (va.z + va.w) + (vb.x + vb.y) + (vb.z + vb.w);
            s2 += (va.x * va.x + va.y * va.y) + (va.z * va.z + va.w * va.w)
                + (vb.x * vb.x + vb.y * vb.y) + (vb.z * vb.z + vb.w * vb.w);
            short8 sv;
            sv[0] = (short)f2bf(va.x); sv[1] = (short)f2bf(va.y);
            sv[2] = (short)f2bf(va.z); sv[3] = (short)f2bf(va.w);
            sv[4] = (short)f2bf(vb.x); sv[5] = (short)f2bf(vb.y);
            sv[6] = (short)f2bf(vb.z); sv[7] = (short)f2bf(vb.w);
            *(short8*)&xs[t * 128 + ((g ^ sw) * 8)] = sv;
        }
        float mu  = s * (1.f / D_);
        float var = s2 * (1.f / D_) - mu * mu;
        mul[t] = mu;
        rsl[t] = rsqrtf(var + EPSLN);
    }
    __syncthreads();

    // ---- MFMA main: wave w -> rows w*64..+63 (4 m-tiles), cols 0..63 (4 n-tiles)
    int wv = t >> 6, lane = t & 63;
    int m16 = lane & 15, quad = lane >> 4;

    f32x4 acc[4][4];
#pragma unroll
    for (int i = 0; i < 4; ++i)
#pragma unroll
        for (int j = 0; j < 4; ++j) acc[i][j] = (f32x4){0.f, 0.f, 0.f, 0.f};

    const unsigned short* Mb = Mt + (size_t)b * E_ * D_;

#pragma unroll
    for (int kc = 0; kc < 4; ++kc) {
        short8 af[4], bf[4];
#pragma unroll
        for (int mt = 0; mt < 4; ++mt) {
            int row = wv * 64 + mt * 16 + m16;
            int g = kc * 4 + quad;
            af[mt] = *(const short8*)&xs[row * 128 + ((g ^ m16) * 8)];
        }
#pragma unroll
        for (int nt = 0; nt < 4; ++nt) {
            bf[nt] = *(const short8*)(Mb + (size_t)(nt * 16 + m16) * D_ + kc * 32 + quad * 8);
        }
#pragma unroll
        for (int mt = 0; mt < 4; ++mt)
#pragma unroll
            for (int nt = 0; nt < 4; ++nt)
                acc[mt][nt] = __builtin_amdgcn_mfma_f32_16x16x32_bf16(
                    af[mt], bf[nt], acc[mt][nt], 0, 0, 0);
    }

    // ---- epilogue: C/D layout col = lane&15, row = quad*4 + reg ----
    size_t outbase = (size_t)(b * N_ + rowbase) * E_;
#pragma unroll
    for (int mt = 0; mt < 4; ++mt) {
        int rb = wv * 64 + mt * 16 + quad * 4;
        float mu0 = mul[rb + 0], rs0 = rsl[rb + 0];
        float mu1 = mul[rb + 1], rs1 = rsl[rb + 1];
        float mu2 = mul[rb + 2], rs2 = rsl[rb + 2];
        float mu3 = mul[rb + 3], rs3 = rsl[rb + 3];
#pragma unroll
        for (int nt = 0; nt < 4; ++nt) {
            int col = nt * 16 + m16;
            float Tc = Tl[col], Cc = Cl[col];
            float* o = out + outbase + (size_t)rb * E_ + col;
            o[0 * E_] = rs0 * (acc[mt][nt][0] - mu0 * Tc) + Cc;
            o[1 * E_] = rs1 * (acc[mt][nt][1] - mu1 * Tc) + Cc;
            o[2 * E_] = rs2 * (acc[mt][nt][2] - mu2 * Tc) + Cc;
            o[3 * E_] = rs3 * (acc[mt][nt][3] - mu3 * Tc) + Cc;
        }
    }
}

extern "C" void kernel_launch(void* const* d_in, const int* in_sizes, int n_in,
                              void* d_out, int out_size, void* d_ws, size_t ws_size,
                              hipStream_t stream) {
    const float* x    = (const float*)d_in[0];
    const float* ln_w = (const float*)d_in[1];
    const float* ln_b = (const float*)d_in[2];
    const float* Wl   = (const float*)d_in[3];
    const float* bl   = (const float*)d_in[4];
    const float* Wr   = (const float*)d_in[5];
    const float* br   = (const float*)d_in[6];
    const float* Wo   = (const float*)d_in[7];
    const float* bo   = (const float*)d_in[8];
    float* out = (float*)d_out;
    char* ws   = (char*)d_ws;

    float*          colacc = (float*)(ws + WSB_COL);
    unsigned short* Mt     = (unsigned short*)(ws + WSB_MT);
    float*          Tg     = (float*)(ws + WSB_T);
    float*          Cg     = (float*)(ws + WSB_C);

    hipMemsetAsync(colacc, 0, B_ * D_ * sizeof(float), stream);

    k_stats<<<dim3(N_ / 64, B_), 256, 0, stream>>>(x, colacc);
    k_combine<<<dim3(4, B_), 256, 0, stream>>>(colacc, ln_w, ln_b, Wl, bl, Wr,
                                               br, Wo, bo, Mt, Tg, Cg);
    k_gemm<<<dim3(N_ / 256, B_), 256, 0, stream>>>(x, Mt, Tg, Cg, out);
}